// Round 7
// baseline (672.792 us; speedup 1.0000x reference)
//
#include <hip/hip_runtime.h>

#define NROW 16384
#define DIM  64
#define TSTEPS 8
#define MAXST 12
#define NBLK 512              /* 512 blocks x 32 rows; 2 blocks/CU co-resident */
#define TPB  512              /* == NBLK: block0 polls one ready-flag per thread */
#define RPB  32
#define MAXSID 96

#define ODE_RTOL 0.01f
#define ODE_ATOL 0.001f

#define C21 ((float)(0.2))
#define C31 ((float)(3.0/40.0))
#define C32 ((float)(9.0/40.0))
#define C41 ((float)(44.0/45.0))
#define C42 ((float)(-56.0/15.0))
#define C43 ((float)(32.0/9.0))
#define C51 ((float)(19372.0/6561.0))
#define C52 ((float)(-25360.0/2187.0))
#define C53 ((float)(64448.0/6561.0))
#define C54 ((float)(-212.0/729.0))
#define C61 ((float)(9017.0/3168.0))
#define C62 ((float)(-355.0/33.0))
#define C63 ((float)(46732.0/5247.0))
#define C64 ((float)(49.0/176.0))
#define C65 ((float)(-5103.0/18656.0))
#define B1  ((float)(35.0/384.0))
#define B3  ((float)(500.0/1113.0))
#define B4  ((float)(125.0/192.0))
#define B5  ((float)(-2187.0/6784.0))
#define B6  ((float)(11.0/84.0))
#define E1  ((float)(35.0/384.0 - 5179.0/57600.0))
#define E3  ((float)(500.0/1113.0 - 7571.0/16695.0))
#define E4  ((float)(125.0/192.0 - 393.0/640.0))
#define E5  ((float)(-2187.0/6784.0 + 92097.0/339200.0))
#define E6  ((float)(11.0/84.0 - 187.0/2100.0))
#define E7  ((float)(-1.0/40.0))

typedef __attribute__((ext_vector_type(8))) short          s8x8;   // 8 bf16
typedef __attribute__((ext_vector_type(8))) unsigned short u16x8;
typedef __attribute__((ext_vector_type(4))) float          f32x4;
#define MFMA16 __builtin_amdgcn_mfma_f32_16x16x32_bf16

// Contention-free grid-barrier state (module globals; zero at load, every used
// slot self-resets to zero before kernel exit; d_ws deliberately untouched).
// No two blocks ever RMW the same address.
__device__ float        g_part [MAXSID * NBLK];  // per-block partials
__device__ unsigned int g_ready[MAXSID * NBLK];  // b -> published (reset by blk0)
__device__ unsigned int g_go   [MAXSID * NBLK];  // blk0 -> b (reset by owner b)
__device__ float        g_tot  [MAXSID];         // deterministic totals

#define A_LD(p)    __hip_atomic_load((p),       __ATOMIC_ACQUIRE, __HIP_MEMORY_SCOPE_AGENT)
#define A_LDX(p)   __hip_atomic_load((p),       __ATOMIC_RELAXED, __HIP_MEMORY_SCOPE_AGENT)
#define A_ST(p,v)  __hip_atomic_store((p), (v), __ATOMIC_RELEASE, __HIP_MEMORY_SCOPE_AGENT)
#define A_STX(p,v) __hip_atomic_store((p), (v), __ATOMIC_RELAXED, __HIP_MEMORY_SCOPE_AGENT)

__device__ __forceinline__ unsigned short bfrn(float x) {   // f32 -> bf16 RNE
  unsigned u = __builtin_bit_cast(unsigned, x);
  u += 0x7FFFu + ((u >> 16) & 1u);
  return (unsigned short)(u >> 16);
}
__device__ __forceinline__ float bf2f(unsigned short h) {
  unsigned u = ((unsigned)h) << 16;
  return __builtin_bit_cast(float, u);
}
// x ~= hi + mid + lo (each bf16); residuals exact in f32 -> ~2^-24 total error
__device__ __forceinline__ void split3(float x, unsigned short& h,
                                       unsigned short& m, unsigned short& lo) {
  h = bfrn(x); float r  = x - bf2f(h);
  m = bfrn(r); float r2 = r - bf2f(m);
  lo = bfrn(r2);
}
// tanh via exp+rcp: ~7 inst, abs err <= ~2.5e-7 (inf-safe: e=inf -> r=1).
__device__ __forceinline__ float fast_tanh(float x) {
  float ax = fabsf(x);
  float e  = __expf(ax + ax);
  float r  = fmaf(-2.0f, __builtin_amdgcn_rcpf(e + 1.0f), 1.0f);
  return copysignf(r, x);
}

__global__ __launch_bounds__(TPB, 4)   // 4 waves/EU -> 2 blocks/CU guaranteed
void ode_dopri5_mfma(const float* __restrict__ vt, const float* __restrict__ y0,
                     const float* __restrict__ W1, const float* __restrict__ b1,
                     const float* __restrict__ W2, const float* __restrict__ b2,
                     float* __restrict__ out) {
  // A-operand fragment planes (bf16x3) for Z and tanh-activations only.
  // u16 index = ((rt*2+ks)*64 + lane_slot)*8 + (k&7),
  //   lane_slot = (row&15) | (((k>>3)&3)<<4), rt=row>>4, ks=k>>5.
  __shared__ __align__(16) unsigned short ZF [3][2048];
  __shared__ __align__(16) unsigned short AFR[3][2048];
  __shared__ float redbuf[8];
  __shared__ float bcast;

  const int tid = threadIdx.x;
  const int l   = tid & 63;
  const int w   = tid >> 6;      // wave 0..7
  const int rt  = w >> 2;        // row-tile 0..1
  const int ct  = w & 3;         // col-tile 0..3
  const int l15 = l & 15;
  const int lq  = l >> 4;        // 0..3
  const int m0  = rt * 16 + lq * 4;   // first owned row
  const int n   = ct * 16 + l15;      // owned column
  const int row0 = blockIdx.x * RPB;

  const int zoff = ((rt * 2 + (n >> 5)) * 64 + ((m0 & 15) | (((n >> 3) & 3) << 4))) * 8 + (n & 7);
  const int ro0 = ((rt * 2 + 0) * 64 + l) * 8, ro1 = ((rt * 2 + 1) * 64 + l) * 8;

  // ---- one-time W staging: ALL THREE planes in VGPRs (48 VGPR total) ----
  s8x8 w1h[2], w1m[2], w1l[2], w2h[2], w2m[2], w2l[2];
#pragma unroll
  for (int ks = 0; ks < 2; ++ks) {
    u16x8 th, tm, tl, sh, sm, sl;
#pragma unroll
    for (int i = 0; i < 8; ++i) {
      unsigned short h, m, lo;
      split3(W1[(ks * 32 + lq * 8 + i) * 64 + n], h, m, lo);
      th[i] = h; tm[i] = m; tl[i] = lo;
      split3(W2[(ks * 32 + lq * 8 + i) * 64 + n], h, m, lo);
      sh[i] = h; sm[i] = m; sl[i] = lo;
    }
    w1h[ks] = __builtin_bit_cast(s8x8, th);
    w1m[ks] = __builtin_bit_cast(s8x8, tm);
    w1l[ks] = __builtin_bit_cast(s8x8, tl);
    w2h[ks] = __builtin_bit_cast(s8x8, sh);
    w2m[ks] = __builtin_bit_cast(s8x8, sm);
    w2l[ks] = __builtin_bit_cast(s8x8, sl);
  }
  const float b1c = b1[n];
  const float b2c = b2[n];

  float y[4], k1[4], k2[4], k3[4], k4[4], k5[4], k6[4], k7[4], y5[4], z[4];

  // f-eval: zv[4] (owner layout == C-frag) -> kout[4]; 2 block barriers.
  auto EVAL = [&](const float* zv, float* kout) {
#pragma unroll
    for (int q = 0; q < 4; ++q) {
      unsigned short h, m, lo; split3(zv[q], h, m, lo);
      ZF[0][zoff + 8 * q] = h; ZF[1][zoff + 8 * q] = m; ZF[2][zoff + 8 * q] = lo;
    }
    __syncthreads();
    f32x4 acc = {b1c, b1c, b1c, b1c};
#pragma unroll
    for (int ks = 0; ks < 2; ++ks) {
      const int ro = ks ? ro1 : ro0;
      s8x8 zh = *(const s8x8*)&ZF[0][ro];
      s8x8 zm = *(const s8x8*)&ZF[1][ro];
      s8x8 zl = *(const s8x8*)&ZF[2][ro];
      acc = MFMA16(zh, w1h[ks], acc, 0, 0, 0);
      acc = MFMA16(zm, w1h[ks], acc, 0, 0, 0);
      acc = MFMA16(zl, w1h[ks], acc, 0, 0, 0);
      acc = MFMA16(zh, w1m[ks], acc, 0, 0, 0);
      acc = MFMA16(zm, w1m[ks], acc, 0, 0, 0);
      acc = MFMA16(zh, w1l[ks], acc, 0, 0, 0);
    }
#pragma unroll
    for (int q = 0; q < 4; ++q) {
      float a = fast_tanh(acc[q]);
      unsigned short h, m, lo; split3(a, h, m, lo);
      AFR[0][zoff + 8 * q] = h; AFR[1][zoff + 8 * q] = m; AFR[2][zoff + 8 * q] = lo;
    }
    __syncthreads();
    f32x4 acc2 = {b2c, b2c, b2c, b2c};
#pragma unroll
    for (int ks = 0; ks < 2; ++ks) {
      const int ro = ks ? ro1 : ro0;
      s8x8 ah = *(const s8x8*)&AFR[0][ro];
      s8x8 am = *(const s8x8*)&AFR[1][ro];
      s8x8 al = *(const s8x8*)&AFR[2][ro];
      acc2 = MFMA16(ah, w2h[ks], acc2, 0, 0, 0);
      acc2 = MFMA16(am, w2h[ks], acc2, 0, 0, 0);
      acc2 = MFMA16(al, w2h[ks], acc2, 0, 0, 0);
      acc2 = MFMA16(ah, w2m[ks], acc2, 0, 0, 0);
      acc2 = MFMA16(am, w2m[ks], acc2, 0, 0, 0);
      acc2 = MFMA16(ah, w2l[ks], acc2, 0, 0, 0);
    }
#pragma unroll
    for (int q = 0; q < 4; ++q) kout[q] = acc2[q];
  };

  const size_t gbase = (size_t)(row0 + m0) * DIM + n;
#pragma unroll
  for (int q = 0; q < 4; ++q) {
    y[q] = y0[gbase + (size_t)q * DIM];
    out[gbase + (size_t)q * DIM] = y[q];
  }

  EVAL(y, k1);   // FSAL seed

  float h = (vt[1] - vt[0]) * 0.1f;
  int sid = 0;

  for (int seg = 0; seg < TSTEPS - 1; ++seg) {
    const float t1 = vt[seg + 1];
    float t = vt[seg];

    for (int st = 0; st < MAXST; ++st) {
      float rem = t1 - t;
      if (!(rem > 1e-9f)) break;
      float htry = fminf(h, rem);

#pragma unroll
      for (int q = 0; q < 4; ++q) z[q] = fmaf(htry, C21 * k1[q], y[q]);
      EVAL(z, k2);
#pragma unroll
      for (int q = 0; q < 4; ++q) {
        float c = fmaf(C32, k2[q], C31 * k1[q]);
        z[q] = fmaf(htry, c, y[q]);
      }
      EVAL(z, k3);
#pragma unroll
      for (int q = 0; q < 4; ++q) {
        float c = C41 * k1[q]; c = fmaf(C42, k2[q], c); c = fmaf(C43, k3[q], c);
        z[q] = fmaf(htry, c, y[q]);
      }
      EVAL(z, k4);
#pragma unroll
      for (int q = 0; q < 4; ++q) {
        float c = C51 * k1[q]; c = fmaf(C52, k2[q], c); c = fmaf(C53, k3[q], c);
        c = fmaf(C54, k4[q], c);
        z[q] = fmaf(htry, c, y[q]);
      }
      EVAL(z, k5);
#pragma unroll
      for (int q = 0; q < 4; ++q) {
        float c = C61 * k1[q]; c = fmaf(C62, k2[q], c); c = fmaf(C63, k3[q], c);
        c = fmaf(C64, k4[q], c); c = fmaf(C65, k5[q], c);
        z[q] = fmaf(htry, c, y[q]);
      }
      EVAL(z, k6);
#pragma unroll
      for (int q = 0; q < 4; ++q) {
        float c = B1 * k1[q]; c = fmaf(B3, k3[q], c); c = fmaf(B4, k4[q], c);
        c = fmaf(B5, k5[q], c); c = fmaf(B6, k6[q], c);
        y5[q] = fmaf(htry, c, y[q]);
      }
      EVAL(y5, k7);

      float accq = 0.f;
#pragma unroll
      for (int q = 0; q < 4; ++q) {
        float e = E1 * k1[q]; e = fmaf(E3, k3[q], e); e = fmaf(E4, k4[q], e);
        e = fmaf(E5, k5[q], e); e = fmaf(E6, k6[q], e); e = fmaf(E7, k7[q], e);
        e *= htry;
        float sc = fmaf(ODE_RTOL, fmaxf(fabsf(y[q]), fabsf(y5[q])), ODE_ATOL);
        float qq = e / sc;
        accq = fmaf(qq, qq, accq);
      }

      // ---- block partial (fixed tree) ----
#pragma unroll
      for (int off = 32; off; off >>= 1) accq += __shfl_xor(accq, off, 64);
      if (l == 0) redbuf[w] = accq;
      __syncthreads();
      if (tid == 0) {
        float bsum = 0.f;
#pragma unroll
        for (int i = 0; i < 8; ++i) bsum += redbuf[i];
        A_STX(&g_part[sid * NBLK + blockIdx.x], bsum);
        A_ST (&g_ready[sid * NBLK + blockIdx.x], 1u);   // release: bsum visible
      }

      // ---- contention-free grid barrier + deterministic device reduce ----
      float tot;
      if (blockIdx.x == 0) {
        // each of the 512 threads polls exactly one block's ready flag
        while (A_LD(&g_ready[sid * NBLK + tid]) == 0u)
          __builtin_amdgcn_s_sleep(1);
        float v = A_LDX(&g_part[sid * NBLK + tid]);
        A_STX(&g_ready[sid * NBLK + tid], 0u);          // self-clean (only blk0)
#pragma unroll
        for (int off = 32; off; off >>= 1) v += __shfl_xor(v, off, 64);
        if (l == 0) redbuf[w] = v;
        __syncthreads();
        if (tid == 0) {
          float s = 0.f;
#pragma unroll
          for (int i = 0; i < 8; ++i) s += redbuf[i];
          A_STX(&g_tot[sid], s);
          bcast = s;
          __threadfence();
        }
        __syncthreads();                                 // tot visible block-wide
        if (tid != 0)                                    // go[b] for b=1..511
          A_ST(&g_go[sid * NBLK + tid], 1u);             // release: tot visible
        tot = bcast;
      } else {
        if (tid == 0) {
          while (A_LD(&g_go[sid * NBLK + blockIdx.x]) == 0u)
            __builtin_amdgcn_s_sleep(1);
          bcast = A_LDX(&g_tot[sid]);
          A_STX(&g_go[sid * NBLK + blockIdx.x], 0u);     // self-clean (owner)
        }
        __syncthreads();
        tot = bcast;
      }

      float err_norm = fmaxf(sqrtf(tot * (1.0f / (float)(NROW * DIM))), 1e-10f);
      bool accept  = (err_norm <= 1.0f);
      float factor = fminf(fmaxf(0.9f * powf(err_norm, -0.2f), 0.2f), 10.0f);
      if (accept) {
        t = t + htry;
#pragma unroll
        for (int q = 0; q < 4; ++q) { y[q] = y5[q]; k1[q] = k7[q]; }  // FSAL
      }
      h = htry * factor;
      ++sid;
    }

#pragma unroll
    for (int q = 0; q < 4; ++q)
      out[((size_t)(seg + 1) * NROW) * DIM + gbase + (size_t)q * DIM] = y[q];
  }
}

extern "C" void kernel_launch(void* const* d_in, const int* in_sizes, int n_in,
                              void* d_out, int out_size, void* d_ws, size_t ws_size,
                              hipStream_t stream) {
  const float* vt = (const float*)d_in[0];
  const float* y0 = (const float*)d_in[1];
  const float* W1 = (const float*)d_in[2];
  const float* b1 = (const float*)d_in[3];
  const float* W2 = (const float*)d_in[4];
  const float* b2 = (const float*)d_in[5];
  float* out = (float*)d_out;
  (void)d_ws; (void)ws_size;

  hipLaunchKernelGGL(ode_dopri5_mfma, dim3(NBLK), dim3(TPB), 0, stream,
                     vt, y0, W1, b1, W2, b2, out);
}

// Round 11
// 182.959 us; speedup vs baseline: 3.6773x; 3.6773x over previous
//
#include <hip/hip_runtime.h>

#define NROW 16384
#define DIM  64
#define TSTEPS 8
#define MAXST 12
#define NBLK 512              /* 512 blocks x 32 rows; 2 blocks/CU co-resident */
#define TPB  512              /* == NBLK: block0 polls one pub-word per thread */
#define RPB  32
#define MAXSID 96

#define ODE_RTOL 0.01f
#define ODE_ATOL 0.001f

#define C21 ((float)(0.2))
#define C31 ((float)(3.0/40.0))
#define C32 ((float)(9.0/40.0))
#define C41 ((float)(44.0/45.0))
#define C42 ((float)(-56.0/15.0))
#define C43 ((float)(32.0/9.0))
#define C51 ((float)(19372.0/6561.0))
#define C52 ((float)(-25360.0/2187.0))
#define C53 ((float)(64448.0/6561.0))
#define C54 ((float)(-212.0/729.0))
#define C61 ((float)(9017.0/3168.0))
#define C62 ((float)(-355.0/33.0))
#define C63 ((float)(46732.0/5247.0))
#define C64 ((float)(49.0/176.0))
#define C65 ((float)(-5103.0/18656.0))
#define B1  ((float)(35.0/384.0))
#define B3  ((float)(500.0/1113.0))
#define B4  ((float)(125.0/192.0))
#define B5  ((float)(-2187.0/6784.0))
#define B6  ((float)(11.0/84.0))
#define E1  ((float)(35.0/384.0 - 5179.0/57600.0))
#define E3  ((float)(500.0/1113.0 - 7571.0/16695.0))
#define E4  ((float)(125.0/192.0 - 393.0/640.0))
#define E5  ((float)(-2187.0/6784.0 + 92097.0/339200.0))
#define E6  ((float)(11.0/84.0 - 187.0/2100.0))
#define E7  ((float)(-1.0/40.0))

typedef __attribute__((ext_vector_type(8))) short          s8x8;   // 8 bf16
typedef __attribute__((ext_vector_type(8))) unsigned short u16x8;
typedef __attribute__((ext_vector_type(4))) float          f32x4;
#define MFMA16 __builtin_amdgcn_mfma_f32_16x16x32_bf16

// Fence-free grid barrier: data rides inside one relaxed 64-bit atomic word
// {flag(hi32), f32(lo32)} -> no acquire/release (and thus NO per-op L2
// writeback/invalidate storms -- that was round 7's 2x regression).
// Module globals: zero at load; every used slot self-resets before kernel
// exit so every call starts identically. d_ws deliberately untouched.
__device__ unsigned long long g_pub[MAXSID * NBLK];  // block b -> blk0
__device__ unsigned long long g_go [MAXSID * NBLK];  // blk0 -> block b

#define U64_LD(p)   __hip_atomic_load((p),       __ATOMIC_RELAXED, __HIP_MEMORY_SCOPE_AGENT)
#define U64_ST(p,v) __hip_atomic_store((p), (v), __ATOMIC_RELAXED, __HIP_MEMORY_SCOPE_AGENT)

__device__ __forceinline__ unsigned long long packf(float f) {
  return (1ull << 32) | (unsigned long long)__builtin_bit_cast(unsigned, f);
}
__device__ __forceinline__ float unpackf(unsigned long long v) {
  return __builtin_bit_cast(float, (unsigned)(v & 0xFFFFFFFFull));
}

__device__ __forceinline__ unsigned short bfrn(float x) {   // f32 -> bf16 RNE
  unsigned u = __builtin_bit_cast(unsigned, x);
  u += 0x7FFFu + ((u >> 16) & 1u);
  return (unsigned short)(u >> 16);
}
__device__ __forceinline__ float bf2f(unsigned short h) {
  unsigned u = ((unsigned)h) << 16;
  return __builtin_bit_cast(float, u);
}
// x ~= hi + mid + lo (each bf16); residuals exact in f32 -> ~2^-24 total error
__device__ __forceinline__ void split3(float x, unsigned short& h,
                                       unsigned short& m, unsigned short& lo) {
  h = bfrn(x); float r  = x - bf2f(h);
  m = bfrn(r); float r2 = r - bf2f(m);
  lo = bfrn(r2);
}
// tanh via exp+rcp: ~7 inst, abs err <= ~2.5e-7 (inf-safe: e=inf -> r=1).
__device__ __forceinline__ float fast_tanh(float x) {
  float ax = fabsf(x);
  float e  = __expf(ax + ax);
  float r  = fmaf(-2.0f, __builtin_amdgcn_rcpf(e + 1.0f), 1.0f);
  return copysignf(r, x);
}

__global__ __launch_bounds__(TPB, 4)   // 4 waves/EU -> 2 blocks/CU guaranteed
void ode_dopri5_mfma(const float* __restrict__ vt, const float* __restrict__ y0,
                     const float* __restrict__ W1, const float* __restrict__ b1,
                     const float* __restrict__ W2, const float* __restrict__ b2,
                     float* __restrict__ out) {
  // A-operand fragment planes (bf16x3) for Z and tanh-activations only.
  // u16 index = ((rt*2+ks)*64 + lane_slot)*8 + (k&7),
  //   lane_slot = (row&15) | (((k>>3)&3)<<4), rt=row>>4, ks=k>>5.
  __shared__ __align__(16) unsigned short ZF [3][2048];
  __shared__ __align__(16) unsigned short AFR[3][2048];
  __shared__ float redbuf[8];
  __shared__ float bcast;

  const int tid = threadIdx.x;
  const int l   = tid & 63;
  const int w   = tid >> 6;      // wave 0..7
  const int rt  = w >> 2;        // row-tile 0..1
  const int ct  = w & 3;         // col-tile 0..3
  const int l15 = l & 15;
  const int lq  = l >> 4;        // 0..3
  const int m0  = rt * 16 + lq * 4;   // first owned row
  const int n   = ct * 16 + l15;      // owned column
  const int row0 = blockIdx.x * RPB;

  const int zoff = ((rt * 2 + (n >> 5)) * 64 + ((m0 & 15) | (((n >> 3) & 3) << 4))) * 8 + (n & 7);
  const int ro0 = ((rt * 2 + 0) * 64 + l) * 8, ro1 = ((rt * 2 + 1) * 64 + l) * 8;

  // ---- one-time W staging: ALL THREE planes in VGPRs (48 VGPR total) ----
  s8x8 w1h[2], w1m[2], w1l[2], w2h[2], w2m[2], w2l[2];
#pragma unroll
  for (int ks = 0; ks < 2; ++ks) {
    u16x8 th, tm, tl, sh, sm, sl;
#pragma unroll
    for (int i = 0; i < 8; ++i) {
      unsigned short h, m, lo;
      split3(W1[(ks * 32 + lq * 8 + i) * 64 + n], h, m, lo);
      th[i] = h; tm[i] = m; tl[i] = lo;
      split3(W2[(ks * 32 + lq * 8 + i) * 64 + n], h, m, lo);
      sh[i] = h; sm[i] = m; sl[i] = lo;
    }
    w1h[ks] = __builtin_bit_cast(s8x8, th);
    w1m[ks] = __builtin_bit_cast(s8x8, tm);
    w1l[ks] = __builtin_bit_cast(s8x8, tl);
    w2h[ks] = __builtin_bit_cast(s8x8, sh);
    w2m[ks] = __builtin_bit_cast(s8x8, sm);
    w2l[ks] = __builtin_bit_cast(s8x8, sl);
  }
  const float b1c = b1[n];
  const float b2c = b2[n];

  float y[4], k1[4], k2[4], k3[4], k4[4], k5[4], k6[4], k7[4], y5[4], z[4];

  // f-eval: zv[4] (owner layout == C-frag) -> kout[4]; 2 block barriers.
  auto EVAL = [&](const float* zv, float* kout) {
#pragma unroll
    for (int q = 0; q < 4; ++q) {
      unsigned short h, m, lo; split3(zv[q], h, m, lo);
      ZF[0][zoff + 8 * q] = h; ZF[1][zoff + 8 * q] = m; ZF[2][zoff + 8 * q] = lo;
    }
    __syncthreads();
    f32x4 acc = {b1c, b1c, b1c, b1c};
#pragma unroll
    for (int ks = 0; ks < 2; ++ks) {
      const int ro = ks ? ro1 : ro0;
      s8x8 zh = *(const s8x8*)&ZF[0][ro];
      s8x8 zm = *(const s8x8*)&ZF[1][ro];
      s8x8 zl = *(const s8x8*)&ZF[2][ro];
      acc = MFMA16(zh, w1h[ks], acc, 0, 0, 0);
      acc = MFMA16(zm, w1h[ks], acc, 0, 0, 0);
      acc = MFMA16(zl, w1h[ks], acc, 0, 0, 0);
      acc = MFMA16(zh, w1m[ks], acc, 0, 0, 0);
      acc = MFMA16(zm, w1m[ks], acc, 0, 0, 0);
      acc = MFMA16(zh, w1l[ks], acc, 0, 0, 0);
    }
#pragma unroll
    for (int q = 0; q < 4; ++q) {
      float a = fast_tanh(acc[q]);
      unsigned short h, m, lo; split3(a, h, m, lo);
      AFR[0][zoff + 8 * q] = h; AFR[1][zoff + 8 * q] = m; AFR[2][zoff + 8 * q] = lo;
    }
    __syncthreads();
    f32x4 acc2 = {b2c, b2c, b2c, b2c};
#pragma unroll
    for (int ks = 0; ks < 2; ++ks) {
      const int ro = ks ? ro1 : ro0;
      s8x8 ah = *(const s8x8*)&AFR[0][ro];
      s8x8 am = *(const s8x8*)&AFR[1][ro];
      s8x8 al = *(const s8x8*)&AFR[2][ro];
      acc2 = MFMA16(ah, w2h[ks], acc2, 0, 0, 0);
      acc2 = MFMA16(am, w2h[ks], acc2, 0, 0, 0);
      acc2 = MFMA16(al, w2h[ks], acc2, 0, 0, 0);
      acc2 = MFMA16(ah, w2m[ks], acc2, 0, 0, 0);
      acc2 = MFMA16(am, w2m[ks], acc2, 0, 0, 0);
      acc2 = MFMA16(ah, w2l[ks], acc2, 0, 0, 0);
    }
#pragma unroll
    for (int q = 0; q < 4; ++q) kout[q] = acc2[q];
  };

  const size_t gbase = (size_t)(row0 + m0) * DIM + n;
#pragma unroll
  for (int q = 0; q < 4; ++q) {
    y[q] = y0[gbase + (size_t)q * DIM];
    out[gbase + (size_t)q * DIM] = y[q];
  }

  EVAL(y, k1);   // FSAL seed

  float h = (vt[1] - vt[0]) * 0.1f;
  int sid = 0;

  for (int seg = 0; seg < TSTEPS - 1; ++seg) {
    const float t1 = vt[seg + 1];
    float t = vt[seg];

    for (int st = 0; st < MAXST; ++st) {
      float rem = t1 - t;
      if (!(rem > 1e-9f)) break;
      float htry = fminf(h, rem);

#pragma unroll
      for (int q = 0; q < 4; ++q) z[q] = fmaf(htry, C21 * k1[q], y[q]);
      EVAL(z, k2);
#pragma unroll
      for (int q = 0; q < 4; ++q) {
        float c = fmaf(C32, k2[q], C31 * k1[q]);
        z[q] = fmaf(htry, c, y[q]);
      }
      EVAL(z, k3);
#pragma unroll
      for (int q = 0; q < 4; ++q) {
        float c = C41 * k1[q]; c = fmaf(C42, k2[q], c); c = fmaf(C43, k3[q], c);
        z[q] = fmaf(htry, c, y[q]);
      }
      EVAL(z, k4);
#pragma unroll
      for (int q = 0; q < 4; ++q) {
        float c = C51 * k1[q]; c = fmaf(C52, k2[q], c); c = fmaf(C53, k3[q], c);
        c = fmaf(C54, k4[q], c);
        z[q] = fmaf(htry, c, y[q]);
      }
      EVAL(z, k5);
#pragma unroll
      for (int q = 0; q < 4; ++q) {
        float c = C61 * k1[q]; c = fmaf(C62, k2[q], c); c = fmaf(C63, k3[q], c);
        c = fmaf(C64, k4[q], c); c = fmaf(C65, k5[q], c);
        z[q] = fmaf(htry, c, y[q]);
      }
      EVAL(z, k6);
#pragma unroll
      for (int q = 0; q < 4; ++q) {
        float c = B1 * k1[q]; c = fmaf(B3, k3[q], c); c = fmaf(B4, k4[q], c);
        c = fmaf(B5, k5[q], c); c = fmaf(B6, k6[q], c);
        y5[q] = fmaf(htry, c, y[q]);
      }
      EVAL(y5, k7);

      float accq = 0.f;
#pragma unroll
      for (int q = 0; q < 4; ++q) {
        float e = E1 * k1[q]; e = fmaf(E3, k3[q], e); e = fmaf(E4, k4[q], e);
        e = fmaf(E5, k5[q], e); e = fmaf(E6, k6[q], e); e = fmaf(E7, k7[q], e);
        e *= htry;
        float sc = fmaf(ODE_RTOL, fmaxf(fabsf(y[q]), fabsf(y5[q])), ODE_ATOL);
        float qq = e / sc;
        accq = fmaf(qq, qq, accq);
      }

      // ---- block partial (fixed tree) ----
#pragma unroll
      for (int off = 32; off; off >>= 1) accq += __shfl_xor(accq, off, 64);
      if (l == 0) redbuf[w] = accq;
      __syncthreads();
      if (tid == 0) {
        float bsum = 0.f;
#pragma unroll
        for (int i = 0; i < 8; ++i) bsum += redbuf[i];
        U64_ST(&g_pub[sid * NBLK + blockIdx.x], packf(bsum));  // one relaxed u64
      }

      // ---- fence-free grid barrier + deterministic device reduce ----
      float tot;
      if (blockIdx.x == 0) {
        // each of the 512 threads polls exactly one block's pub word
        unsigned long long pv;
        while (((pv = U64_LD(&g_pub[sid * NBLK + tid])) >> 32) == 0ull)
          __builtin_amdgcn_s_sleep(1);
        float v = unpackf(pv);
        U64_ST(&g_pub[sid * NBLK + tid], 0ull);        // self-clean (only blk0)
#pragma unroll
        for (int off = 32; off; off >>= 1) v += __shfl_xor(v, off, 64);
        if (l == 0) redbuf[w] = v;
        __syncthreads();
        if (tid == 0) {
          float s = 0.f;
#pragma unroll
          for (int i = 0; i < 8; ++i) s += redbuf[i];
          bcast = s;
        }
        __syncthreads();                               // s visible block-wide
        tot = bcast;
        if (tid != 0)                                  // go[b] for b=1..511
          U64_ST(&g_go[sid * NBLK + tid], packf(tot)); // tot rides in the word
      } else {
        if (tid == 0) {
          unsigned long long gv;
          while (((gv = U64_LD(&g_go[sid * NBLK + blockIdx.x])) >> 32) == 0ull)
            __builtin_amdgcn_s_sleep(1);
          bcast = unpackf(gv);
          U64_ST(&g_go[sid * NBLK + blockIdx.x], 0ull); // self-clean (owner)
        }
        __syncthreads();
        tot = bcast;
      }

      float err_norm = fmaxf(sqrtf(tot * (1.0f / (float)(NROW * DIM))), 1e-10f);
      bool accept  = (err_norm <= 1.0f);
      float factor = fminf(fmaxf(0.9f * powf(err_norm, -0.2f), 0.2f), 10.0f);
      if (accept) {
        t = t + htry;
#pragma unroll
        for (int q = 0; q < 4; ++q) { y[q] = y5[q]; k1[q] = k7[q]; }  // FSAL
      }
      h = htry * factor;
      ++sid;
    }

#pragma unroll
    for (int q = 0; q < 4; ++q)
      out[((size_t)(seg + 1) * NROW) * DIM + gbase + (size_t)q * DIM] = y[q];
  }
}

extern "C" void kernel_launch(void* const* d_in, const int* in_sizes, int n_in,
                              void* d_out, int out_size, void* d_ws, size_t ws_size,
                              hipStream_t stream) {
  const float* vt = (const float*)d_in[0];
  const float* y0 = (const float*)d_in[1];
  const float* W1 = (const float*)d_in[2];
  const float* b1 = (const float*)d_in[3];
  const float* W2 = (const float*)d_in[4];
  const float* b2 = (const float*)d_in[5];
  float* out = (float*)d_out;
  (void)d_ws; (void)ws_size;

  hipLaunchKernelGGL(ode_dopri5_mfma, dim3(NBLK), dim3(TPB), 0, stream,
                     vt, y0, W1, b1, W2, b2, out);
}